// Round 18
// baseline (1001.279 us; speedup 1.0000x reference)
//
#include <hip/hip_runtime.h>
#include <math.h>

// ---------------- problem constants ----------------
#define N_DRUGS 4000
#define NN      8264            // total nodes
#define IN_DIM  1613
#define NRELS   4
#define DD1     1340
#define DD2     920
#define DD3     740
#define NEDGE   100000
#define NSEG    (NN * NRELS)    // 33056

// padded dims
#define K1P     1632            // IN_DIM -> 51*32
#define K2P     1344            // DD1 -> 42*32
#define K3P     928             // DD2 -> 29*32
#define N1PAD   1408            // DD1 -> 11*128 (weight slot width)
#define N2PAD   1024            // DD2 -> 8*128
#define N3PAD   768             // DD3 -> 6*128
#define MT      65              // ceil(NN/128)

typedef unsigned short u16;
typedef __attribute__((ext_vector_type(8))) short short8;
typedef __attribute__((ext_vector_type(4))) short short4v;
typedef __attribute__((ext_vector_type(4))) float floatx4;

__device__ __forceinline__ u16 f2bf(float f) {
  union { float f; unsigned u; } v; v.f = f;
  unsigned u = v.u + 0x7fffu + ((v.u >> 16) & 1u);   // RNE
  return (u16)(u >> 16);
}
__device__ __forceinline__ float bf2f(u16 h) {
  union { unsigned u; float f; } v; v.u = ((unsigned)h) << 16;
  return v.f;
}

// async global->LDS DMA, 16 bytes per lane. LDS dest must be wave-uniform
// base + lane*16 (linear); swizzling is done on the GLOBAL source address.
__device__ __forceinline__ void gload16(const u16* g, u16* l) {
  __builtin_amdgcn_global_load_lds(
      (const __attribute__((address_space(1))) unsigned int*)g,
      (__attribute__((address_space(3))) unsigned int*)l, 16, 0, 0);
}

// ---------------- small utility kernels ----------------
__global__ void k_zero_i32(int* p, int n) {
  int i = blockIdx.x * 256 + threadIdx.x;
  if (i < n) p[i] = 0;
}

__global__ void k_zero_u16v(u16* p, long long nvec) {  // zeros 8 u16 per thread
  long long i = (long long)blockIdx.x * 256 + threadIdx.x;
  if (i < nvec) {
    short8 z = {0,0,0,0,0,0,0,0};
    *((short8*)p + i) = z;
  }
}

__global__ void k_copy_i32(const int* a, int* b, int n) {
  int i = blockIdx.x * 256 + threadIdx.x;
  if (i < n) b[i] = a[i];
}

// ---------------- CSR build (counting sort by segment = dst*4 + rel) ------
__global__ void k_hist(const int* __restrict__ ei, const int* __restrict__ et,
                       int* __restrict__ counts) {
  int e = blockIdx.x * 256 + threadIdx.x;
  if (e < NEDGE) {
    int dst = ei[NEDGE + e];
    atomicAdd(&counts[dst * 4 + et[e]], 1);
  }
}

__global__ void k_scan(const int* __restrict__ counts, int* __restrict__ offsets) {
  __shared__ int part[1024];
  int tid = threadIdx.x;
  const int chunk = (NSEG + 1023) / 1024;  // 33
  int lo = tid * chunk, hi = min(lo + chunk, NSEG);
  int s = 0;
  for (int i = lo; i < hi; i++) s += counts[i];
  part[tid] = s;
  __syncthreads();
  for (int off = 1; off < 1024; off <<= 1) {
    int v = (tid >= off) ? part[tid - off] : 0;
    __syncthreads();
    part[tid] += v;
    __syncthreads();
  }
  int base = (tid == 0) ? 0 : part[tid - 1];
  for (int i = lo; i < hi; i++) { offsets[i] = base; base += counts[i]; }
  if (tid == 0) offsets[NSEG] = part[1023];
}

__global__ void k_fill(const int* __restrict__ ei, const int* __restrict__ et,
                       int* __restrict__ cursors, int* __restrict__ ssrc) {
  int e = blockIdx.x * 256 + threadIdx.x;
  if (e < NEDGE) {
    int src = ei[e], dst = ei[NEDGE + e];
    int pos = atomicAdd(&cursors[dst * 4 + et[e]], 1);
    if (pos < NEDGE) ssrc[pos] = src;
  }
}

// ---------------- feature builder: xf = concat(x, gene_emb) in bf16 -------
__global__ void k_build_xf(const float* __restrict__ x, const float* __restrict__ gene,
                           u16* __restrict__ xf) {
  int n = blockIdx.x;
  const float* srow = (n < N_DRUGS) ? (x + (long long)n * IN_DIM)
                                    : (gene + (long long)(n - N_DRUGS) * IN_DIM);
  u16* dst = xf + (long long)n * K1P;
  for (int f = threadIdx.x; f < K1P; f += 256)
    dst[f] = (f < IN_DIM) ? f2bf(srow[f]) : (u16)0;
}

// f32 (K x N, row-major) -> bf16 out[n][k], tiled transpose; batched over z
__global__ void k_transpose(const float* __restrict__ in, int K, int N,
                            u16* __restrict__ out, int ldd,
                            long long strideIn, long long strideOut) {
  __shared__ float t[32][33];
  const float* inp = in + (long long)blockIdx.z * strideIn;
  u16* outp = out + (long long)blockIdx.z * strideOut;
  int k0 = blockIdx.x * 32, n0 = blockIdx.y * 32;
  int tx = threadIdx.x, ty = threadIdx.y;
  for (int i = ty; i < 32; i += 8) {
    int k = k0 + i, n = n0 + tx;
    t[i][tx] = (k < K && n < N) ? inp[(long long)k * N + n] : 0.f;
  }
  __syncthreads();
  for (int i = ty; i < 32; i += 8) {
    int n = n0 + i, k = k0 + tx;
    if (n < N && k < K) outp[(long long)n * ldd + k] = f2bf(t[tx][i]);
  }
}

// per-node mean over gathered T rows for TWO relations, accumulate into bf16
// HACC. Round-14: short8 (16B/lane, G13 sweet spot). All row strides are
// 16B-aligned (ldT 2816/2048, slotOfs 1408/1024, ldH 1344/928 u16 = even*8).
// Per-f edge accumulation order unchanged -> bit-identical. Tail (F&7==4
// for F=1340) handled scalar by thread 0.
__global__ void k_agg2(const u16* __restrict__ T, int ldT, int slotOfs,
                       u16* __restrict__ HACC, int ldH, int F,
                       const int* __restrict__ offsets, const int* __restrict__ ssrc,
                       int rbase, int init) {
  int node = blockIdx.x;
  int s0 = node * 4 + rbase;
  int b0 = offsets[s0],     e0 = offsets[s0 + 1];
  int b1 = offsets[s0 + 1], e1 = offsets[s0 + 2];
  float inv0 = (e0 > b0) ? 1.0f / (float)(e0 - b0) : 0.0f;
  float inv1 = (e1 > b1) ? 1.0f / (float)(e1 - b1) : 0.0f;
  u16* o = HACC + (long long)node * ldH;
  int F8 = F >> 3;                       // 1340/8=167, 920/8=115
  for (int f8 = threadIdx.x; f8 < F8; f8 += 256) {
    int fo = f8 << 3;
    float a0=0.f,a1=0.f,a2=0.f,a3=0.f,a4=0.f,a5=0.f,a6=0.f,a7=0.f;
    for (int e = b0; e < e0; e++) {
      short8 v = *(const short8*)(T + (long long)ssrc[e] * ldT + fo);
      a0 += bf2f((u16)v[0]); a1 += bf2f((u16)v[1]);
      a2 += bf2f((u16)v[2]); a3 += bf2f((u16)v[3]);
      a4 += bf2f((u16)v[4]); a5 += bf2f((u16)v[5]);
      a6 += bf2f((u16)v[6]); a7 += bf2f((u16)v[7]);
    }
    float c0=0.f,c1=0.f,c2=0.f,c3=0.f,c4=0.f,c5=0.f,c6=0.f,c7=0.f;
    for (int e = b1; e < e1; e++) {
      short8 v = *(const short8*)(T + (long long)ssrc[e] * ldT + slotOfs + fo);
      c0 += bf2f((u16)v[0]); c1 += bf2f((u16)v[1]);
      c2 += bf2f((u16)v[2]); c3 += bf2f((u16)v[3]);
      c4 += bf2f((u16)v[4]); c5 += bf2f((u16)v[5]);
      c6 += bf2f((u16)v[6]); c7 += bf2f((u16)v[7]);
    }
    float r0 = a0*inv0 + c0*inv1, r1 = a1*inv0 + c1*inv1;
    float r2 = a2*inv0 + c2*inv1, r3 = a3*inv0 + c3*inv1;
    float r4 = a4*inv0 + c4*inv1, r5 = a5*inv0 + c5*inv1;
    float r6 = a6*inv0 + c6*inv1, r7 = a7*inv0 + c7*inv1;
    if (!init) {
      short8 pv = *(const short8*)(o + fo);
      r0 += bf2f((u16)pv[0]); r1 += bf2f((u16)pv[1]);
      r2 += bf2f((u16)pv[2]); r3 += bf2f((u16)pv[3]);
      r4 += bf2f((u16)pv[4]); r5 += bf2f((u16)pv[5]);
      r6 += bf2f((u16)pv[6]); r7 += bf2f((u16)pv[7]);
    }
    short8 ov;
    ov[0] = (short)f2bf(r0); ov[1] = (short)f2bf(r1);
    ov[2] = (short)f2bf(r2); ov[3] = (short)f2bf(r3);
    ov[4] = (short)f2bf(r4); ov[5] = (short)f2bf(r5);
    ov[6] = (short)f2bf(r6); ov[7] = (short)f2bf(r7);
    *(short8*)(o + fo) = ov;
  }
  if ((F & 7) && threadIdx.x == 0) {       // scalar tail (4 feats for F=1340)
    for (int f = F & ~7; f < F; f++) {
      float a = 0.f, c = 0.f;
      for (int e = b0; e < e0; e++) a += bf2f(T[(long long)ssrc[e] * ldT + f]);
      for (int e = b1; e < e1; e++) c += bf2f(T[(long long)ssrc[e] * ldT + slotOfs + f]);
      float r = a * inv0 + c * inv1;
      if (!init) r += bf2f(o[f]);
      o[f] = f2bf(r);
    }
  }
}

// ---------------- bf16 MFMA GEMM: C = act(A @ B^T + Cacc + bias) ----------
// Round-14 A/B: k_gemm3 = measured-good 3-stage (137us, MfmaUtil 23%);
// k_gemm4 = 4-stage (64KB LDS, hard 2 blocks/CU, 3-iter latency cover,
// vmcnt(8)). First L1 pair-GEMM runs k_gemm4, second (identical workload)
// runs k_gemm3 -> within-run per-dispatch A/B isolates cover-vs-occupancy.
// Both: inline-asm ds_read_b128 (keeps hipcc from inserting vmcnt(0) drains
// against the DMA), lgkmcnt(0)+sched_barrier before MFMAs (rule #18).
#define TBUF (128 * 32)

__global__ __launch_bounds__(256)
void k_gemm3(const u16* __restrict__ A, int lda,
             const u16* __restrict__ B, int ldb, int ksteps,
             void* __restrict__ Cout, int ldc,
             const u16* __restrict__ Cacc, int ldacc,
             int nreal, int nlimit, int mlimit,
             const float* __restrict__ bias, int relu, int f32out,
             int mtiles, int ntiles)
{
  int f = blockIdx.x;
  int xr = f & 7, q = f >> 3;
  int Ma = (mtiles + 7) >> 3;
  int ncol = q / Ma;
  int mi = ((q - ncol * Ma) << 3) + xr;
  if (mi >= mtiles) return;

  __shared__ __align__(16) u16 At[3 * TBUF];   // 24 KB
  __shared__ __align__(16) u16 Bt[3 * TBUF];   // 24 KB
  int tid = threadIdx.x;
  int wave = tid >> 6, lane = tid & 63;
  int wm = (wave >> 1) << 6, wn = (wave & 1) << 6;
  int qd = lane >> 4, l16 = lane & 15;

  const u16* Ag = A + (long long)mi * 128 * lda;
  const u16* Bg = B + (long long)ncol * 128 * ldb;

  int row = tid >> 2, cc = tid & 3;
  int swc = cc ^ ((row >> 1) & 3);
  const u16* gA0 = Ag + (long long)row * lda + swc * 8;
  const u16* gA1 = Ag + (long long)(row + 64) * lda + swc * 8;
  const u16* gB0 = Bg + (long long)row * ldb + swc * 8;
  const u16* gB1 = Bg + (long long)(row + 64) * ldb + swc * 8;
  int d0 = tid * 8;
  int d1 = tid * 8 + 64 * 32;
  int rofs = ((qd ^ ((l16 >> 1) & 3)) << 3);

  unsigned baseA = (unsigned)(unsigned long long)(void*)At;
  unsigned baseB = (unsigned)(unsigned long long)(void*)Bt;
  unsigned offA[4], offB[4];
#pragma unroll
  for (int i = 0; i < 4; i++) {
    offA[i] = (unsigned)(((wm + i * 16 + l16) * 32 + rofs) * 2);
    offB[i] = (unsigned)(((wn + i * 16 + l16) * 32 + rofs) * 2);
  }

  gload16(gA0, At + d0); gload16(gA1, At + d1);
  gload16(gB0, Bt + d0); gload16(gB1, Bt + d1);
  if (ksteps > 1) {
    gload16(gA0 + 32, At + TBUF + d0); gload16(gA1 + 32, At + TBUF + d1);
    gload16(gB0 + 32, Bt + TBUF + d0); gload16(gB1 + 32, Bt + TBUF + d1);
  }

  floatx4 acc[4][4] = {};
  int bs = 0;

  for (int ks = 0; ks < ksteps; ks++) {
    if (ks + 1 < ksteps) asm volatile("s_waitcnt vmcnt(4)" ::: "memory");
    else                 asm volatile("s_waitcnt vmcnt(0)" ::: "memory");
    __builtin_amdgcn_s_barrier();
    __builtin_amdgcn_sched_barrier(0);
    if (ks + 2 < ksteps) {
      int ns = bs + 2; if (ns >= 3) ns -= 3;
      int kb = (ks + 2) * 32;
      u16* An = At + ns * TBUF;
      u16* Bn = Bt + ns * TBUF;
      gload16(gA0 + kb, An + d0); gload16(gA1 + kb, An + d1);
      gload16(gB0 + kb, Bn + d0); gload16(gB1 + kb, Bn + d1);
    }
    unsigned sb = (unsigned)(bs * (TBUF * 2));
    short8 af[4], bfr[4];
#pragma unroll
    for (int i = 0; i < 4; i++)
      asm volatile("ds_read_b128 %0, %1" : "=v"(af[i]) : "v"(baseA + sb + offA[i]));
#pragma unroll
    for (int j = 0; j < 4; j++)
      asm volatile("ds_read_b128 %0, %1" : "=v"(bfr[j]) : "v"(baseB + sb + offB[j]));
    asm volatile("s_waitcnt lgkmcnt(0)" ::: "memory");
    __builtin_amdgcn_sched_barrier(0);
#pragma unroll
    for (int i = 0; i < 4; i++)
#pragma unroll
      for (int j = 0; j < 4; j++)
        acc[i][j] = __builtin_amdgcn_mfma_f32_16x16x32_bf16(af[i], bfr[j], acc[i][j], 0, 0, 0);
    bs++; if (bs >= 3) bs = 0;
  }

#pragma unroll
  for (int i = 0; i < 4; i++) {
#pragma unroll
    for (int j = 0; j < 4; j++) {
      int col = ncol * 128 + wn + j * 16 + l16;
      if (col >= nlimit) continue;
      float bv = (bias && col < nreal) ? bias[col] : 0.f;
#pragma unroll
      for (int rg = 0; rg < 4; rg++) {
        int rowc = mi * 128 + wm + i * 16 + qd * 4 + rg;
        if (rowc >= mlimit) continue;
        float v = 0.f;
        if (col < nreal) {
          v = acc[i][j][rg] + bv;
          if (Cacc) v += bf2f(Cacc[(long long)rowc * ldacc + col]);
          if (relu) v = fmaxf(v, 0.f);
        }
        if (f32out) ((float*)Cout)[(long long)rowc * ldc + col] = v;
        else        ((u16*)Cout)[(long long)rowc * ldc + col] = f2bf(v);
      }
    }
  }
}

__global__ __launch_bounds__(256)
void k_gemm4(const u16* __restrict__ A, int lda,
             const u16* __restrict__ B, int ldb, int ksteps,
             void* __restrict__ Cout, int ldc,
             const u16* __restrict__ Cacc, int ldacc,
             int nreal, int nlimit, int mlimit,
             const float* __restrict__ bias, int relu, int f32out,
             int mtiles, int ntiles)
{
  int f = blockIdx.x;
  int xr = f & 7, q = f >> 3;
  int Ma = (mtiles + 7) >> 3;
  int ncol = q / Ma;
  int mi = ((q - ncol * Ma) << 3) + xr;
  if (mi >= mtiles) return;

  __shared__ __align__(16) u16 At[4 * TBUF];   // 32 KB
  __shared__ __align__(16) u16 Bt[4 * TBUF];   // 32 KB (64 KB -> 2 blocks/CU)
  int tid = threadIdx.x;
  int wave = tid >> 6, lane = tid & 63;
  int wm = (wave >> 1) << 6, wn = (wave & 1) << 6;
  int qd = lane >> 4, l16 = lane & 15;

  const u16* Ag = A + (long long)mi * 128 * lda;
  const u16* Bg = B + (long long)ncol * 128 * ldb;

  int row = tid >> 2, cc = tid & 3;
  int swc = cc ^ ((row >> 1) & 3);
  const u16* gA0 = Ag + (long long)row * lda + swc * 8;
  const u16* gA1 = Ag + (long long)(row + 64) * lda + swc * 8;
  const u16* gB0 = Bg + (long long)row * ldb + swc * 8;
  const u16* gB1 = Bg + (long long)(row + 64) * ldb + swc * 8;
  int d0 = tid * 8;
  int d1 = tid * 8 + 64 * 32;
  int rofs = ((qd ^ ((l16 >> 1) & 3)) << 3);

  unsigned baseA = (unsigned)(unsigned long long)(void*)At;
  unsigned baseB = (unsigned)(unsigned long long)(void*)Bt;
  unsigned offA[4], offB[4];
#pragma unroll
  for (int i = 0; i < 4; i++) {
    offA[i] = (unsigned)(((wm + i * 16 + l16) * 32 + rofs) * 2);
    offB[i] = (unsigned)(((wn + i * 16 + l16) * 32 + rofs) * 2);
  }

  // prologue: stages 0..2 in flight (12 loads)
  gload16(gA0, At + d0); gload16(gA1, At + d1);
  gload16(gB0, Bt + d0); gload16(gB1, Bt + d1);
  if (ksteps > 1) {
    gload16(gA0 + 32, At + TBUF + d0); gload16(gA1 + 32, At + TBUF + d1);
    gload16(gB0 + 32, Bt + TBUF + d0); gload16(gB1 + 32, Bt + TBUF + d1);
  }
  if (ksteps > 2) {
    gload16(gA0 + 64, At + 2 * TBUF + d0); gload16(gA1 + 64, At + 2 * TBUF + d1);
    gload16(gB0 + 64, Bt + 2 * TBUF + d0); gload16(gB1 + 64, Bt + 2 * TBUF + d1);
  }

  floatx4 acc[4][4] = {};
  int bs = 0;                                  // ks % 4

  for (int ks = 0; ks < ksteps; ks++) {
    int rem = ksteps - 1 - ks;                 // later stages still outstanding
    if (rem >= 2)      asm volatile("s_waitcnt vmcnt(8)" ::: "memory");
    else if (rem == 1) asm volatile("s_waitcnt vmcnt(4)" ::: "memory");
    else               asm volatile("s_waitcnt vmcnt(0)" ::: "memory");
    __builtin_amdgcn_s_barrier();
    __builtin_amdgcn_sched_barrier(0);
    if (ks + 3 < ksteps) {                     // refill buf[(ks+3)%4] == buf[(ks-1)%4]
      int ns = (bs + 3) & 3;
      int kb = (ks + 3) * 32;
      u16* An = At + ns * TBUF;
      u16* Bn = Bt + ns * TBUF;
      gload16(gA0 + kb, An + d0); gload16(gA1 + kb, An + d1);
      gload16(gB0 + kb, Bn + d0); gload16(gB1 + kb, Bn + d1);
    }
    unsigned sb = (unsigned)(bs * (TBUF * 2));
    short8 af[4], bfr[4];
#pragma unroll
    for (int i = 0; i < 4; i++)
      asm volatile("ds_read_b128 %0, %1" : "=v"(af[i]) : "v"(baseA + sb + offA[i]));
#pragma unroll
    for (int j = 0; j < 4; j++)
      asm volatile("ds_read_b128 %0, %1" : "=v"(bfr[j]) : "v"(baseB + sb + offB[j]));
    asm volatile("s_waitcnt lgkmcnt(0)" ::: "memory");
    __builtin_amdgcn_sched_barrier(0);
#pragma unroll
    for (int i = 0; i < 4; i++)
#pragma unroll
      for (int j = 0; j < 4; j++)
        acc[i][j] = __builtin_amdgcn_mfma_f32_16x16x32_bf16(af[i], bfr[j], acc[i][j], 0, 0, 0);
    bs = (bs + 1) & 3;
  }

#pragma unroll
  for (int i = 0; i < 4; i++) {
#pragma unroll
    for (int j = 0; j < 4; j++) {
      int col = ncol * 128 + wn + j * 16 + l16;
      if (col >= nlimit) continue;
      float bv = (bias && col < nreal) ? bias[col] : 0.f;
#pragma unroll
      for (int rg = 0; rg < 4; rg++) {
        int rowc = mi * 128 + wm + i * 16 + qd * 4 + rg;
        if (rowc >= mlimit) continue;
        float v = 0.f;
        if (col < nreal) {
          v = acc[i][j][rg] + bv;
          if (Cacc) v += bf2f(Cacc[(long long)rowc * ldacc + col]);
          if (relu) v = fmaxf(v, 0.f);
        }
        if (f32out) ((float*)Cout)[(long long)rowc * ldc + col] = v;
        else        ((u16*)Cout)[(long long)rowc * ldc + col] = f2bf(v);
      }
    }
  }
}

// ---------------- final tiny layer: logits + log_softmax ----------------
__global__ void k_lin2(const float* __restrict__ emb, const float* __restrict__ w,
                       const float* __restrict__ b, float* __restrict__ out) {
  int node = blockIdx.x * 4 + (threadIdx.x >> 6);
  int lane = threadIdx.x & 63;
  if (node >= NN) return;
  const float* e = emb + (long long)node * DD3;
  float a0 = 0.f, a1 = 0.f;
  for (int f = lane; f < DD3; f += 64) {
    float v = e[f];
    a0 += v * w[2 * f];
    a1 += v * w[2 * f + 1];
  }
  for (int off = 32; off > 0; off >>= 1) {
    a0 += __shfl_down(a0, off);
    a1 += __shfl_down(a1, off);
  }
  if (lane == 0) {
    a0 += b[0]; a1 += b[1];
    float m = fmaxf(a0, a1);
    float ls = m + logf(expf(a0 - m) + expf(a1 - m));
    out[(long long)node * 2]     = a0 - ls;
    out[(long long)node * 2 + 1] = a1 - ls;
  }
}

// ---------------- launch ----------------
extern "C" void kernel_launch(void* const* d_in, const int* in_sizes, int n_in,
                              void* d_out, int out_size, void* d_ws, size_t ws_size,
                              hipStream_t stream)
{
  const float* x      = (const float*)d_in[0];
  const float* gene   = (const float*)d_in[1];
  const float* w_rel1 = (const float*)d_in[2];
  const float* root1  = (const float*)d_in[3];
  const float* b1     = (const float*)d_in[4];
  const float* w_rel2 = (const float*)d_in[5];
  const float* root2  = (const float*)d_in[6];
  const float* b2     = (const float*)d_in[7];
  const float* lin1_w = (const float*)d_in[8];
  const float* lin1_b = (const float*)d_in[9];
  const float* lin2_w = (const float*)d_in[10];
  const float* lin2_b = (const float*)d_in[11];
  const int*   ei     = (const int*)d_in[12];
  const int*   et     = (const int*)d_in[13];
  float* out = (float*)d_out;

  // workspace layout (~142 MB total; known-good budget 155.6 MB)
  char* ws = (char*)d_ws;
  size_t off = 0;
  auto alloc = [&](size_t bytes) -> void* {
    void* p = ws + off;
    off += (bytes + 255) & ~(size_t)255;
    return p;
  };
  const size_t W1SLOT = (size_t)N1PAD * K1P;
  const size_t W2SLOT = (size_t)N2PAD * K2P;
  u16* XF   = (u16*)alloc((size_t)NN * K1P * 2);     // reused as H2 (NN x K3P) later
  u16* T    = (u16*)alloc((size_t)NN * 2 * N1PAD * 2); // 2-slot transform output
  u16* HACC = (u16*)alloc((size_t)NN * K2P * 2);     // bf16 aggregation accumulator
  u16* H1   = (u16*)alloc((size_t)NN * K2P * 2);
  u16* W1P  = (u16*)alloc(2 * W1SLOT * 2);           // pair slot (reused r0r1 -> r2r3)
  u16* W1R  = (u16*)alloc(W1SLOT * 2);               // root slot
  u16* W2P  = (u16*)alloc(2 * W2SLOT * 2);
  u16* W2R  = (u16*)alloc(W2SLOT * 2);
  u16* W3T  = (u16*)alloc((size_t)N3PAD * K3P * 2);
  int* counts  = (int*)alloc((NSEG + 1) * 4);        // reused as cursors
  int* offsets = (int*)alloc((NSEG + 1) * 4);
  int* ssrc    = (int*)alloc((size_t)NEDGE * 4);
  u16* H2 = XF;                                      // alias: XF dead after L1 root GEMM
  float* emb = out + 2 * NN;   // d_out = [log_softmax 8264x2][emb 8264x740]

  if (off > ws_size) return;   // diagnostic: stub-like absmax instead of GPU fault

  // ---- CSR build ----
  k_zero_i32<<<(NSEG + 1 + 255) / 256, 256, 0, stream>>>(counts, NSEG + 1);
  k_hist<<<(NEDGE + 255) / 256, 256, 0, stream>>>(ei, et, counts);
  k_scan<<<1, 1024, 0, stream>>>(counts, offsets);
  k_copy_i32<<<(NSEG + 255) / 256, 256, 0, stream>>>(offsets, counts, NSEG); // counts = cursors
  k_fill<<<(NEDGE + 255) / 256, 256, 0, stream>>>(ei, et, counts, ssrc);

  // ---- weights: zero pads once (transposes never touch pad rows/cols) ----
  long long wtot = 3LL * W1SLOT + 3LL * W2SLOT + (long long)N3PAD * K3P;
  k_zero_u16v<<<(unsigned)((wtot / 8 + 255) / 256), 256, 0, stream>>>(W1P, wtot / 8);
  dim3 tb(32, 8);
  dim3 g_t1((IN_DIM + 31) / 32, (DD1 + 31) / 32, 2);
  dim3 g_t1s((IN_DIM + 31) / 32, (DD1 + 31) / 32, 1);
  dim3 g_t2((DD1 + 31) / 32, (DD2 + 31) / 32, 2);
  dim3 g_t2s((DD1 + 31) / 32, (DD2 + 31) / 32, 1);

  // ---- input features ----
  k_build_xf<<<NN, 256, 0, stream>>>(x, gene, XF);

  // XCD-chunked 1D grids: 8 * ceil(MT/8) * ntiles
  const int Ma8 = 8 * ((MT + 7) / 8);          // 72
  const int gP1 = Ma8 * (2 * N1PAD / 128);     // 1584
  const int gR1 = Ma8 * (N1PAD / 128);         // 792
  const int gP2 = Ma8 * (2 * N2PAD / 128);     // 1152
  const int gR2 = Ma8 * (N2PAD / 128);         // 576
  const int gL3 = Ma8 * (N3PAD / 128);         // 432

  // ---- layer 1 ----
  k_transpose<<<g_t1, tb, 0, stream>>>(w_rel1, IN_DIM, DD1, W1P, K1P,
                                       (long long)IN_DIM * DD1, (long long)W1SLOT);
  k_gemm4<<<gP1, 256, 0, stream>>>(XF, K1P, W1P, K1P, K1P / 32,   // A/B: 4-stage
      T, 2 * N1PAD, (const u16*)nullptr, 0, 2 * N1PAD, 2 * N1PAD, NN,
      (const float*)nullptr, 0, 0, MT, 2 * N1PAD / 128);
  k_agg2<<<NN, 256, 0, stream>>>(T, 2 * N1PAD, N1PAD, HACC, K2P, DD1, offsets, ssrc, 0, 1);
  k_transpose<<<g_t1, tb, 0, stream>>>(w_rel1 + 2LL * IN_DIM * DD1, IN_DIM, DD1, W1P, K1P,
                                       (long long)IN_DIM * DD1, (long long)W1SLOT);
  k_gemm3<<<gP1, 256, 0, stream>>>(XF, K1P, W1P, K1P, K1P / 32,   // A/B: 3-stage control
      T, 2 * N1PAD, (const u16*)nullptr, 0, 2 * N1PAD, 2 * N1PAD, NN,
      (const float*)nullptr, 0, 0, MT, 2 * N1PAD / 128);
  k_agg2<<<NN, 256, 0, stream>>>(T, 2 * N1PAD, N1PAD, HACC, K2P, DD1, offsets, ssrc, 2, 0);
  k_transpose<<<g_t1s, tb, 0, stream>>>(root1, IN_DIM, DD1, W1R, K1P, 0, 0);
  k_gemm3<<<gR1, 256, 0, stream>>>(XF, K1P, W1R, K1P, K1P / 32,
      H1, K2P, HACC, K2P, DD1, K2P, NN, b1, 1, 0, MT, N1PAD / 128);

  // ---- layer 2 ----
  k_transpose<<<g_t2, tb, 0, stream>>>(w_rel2, DD1, DD2, W2P, K2P,
                                       (long long)DD1 * DD2, (long long)W2SLOT);
  k_gemm3<<<gP2, 256, 0, stream>>>(H1, K2P, W2P, K2P, K2P / 32,
      T, 2 * N2PAD, (const u16*)nullptr, 0, 2 * N2PAD, 2 * N2PAD, NN,
      (const float*)nullptr, 0, 0, MT, 2 * N2PAD / 128);
  k_agg2<<<NN, 256, 0, stream>>>(T, 2 * N2PAD, N2PAD, HACC, K3P, DD2, offsets, ssrc, 0, 1);
  k_transpose<<<g_t2, tb, 0, stream>>>(w_rel2 + 2LL * DD1 * DD2, DD1, DD2, W2P, K2P,
                                       (long long)DD1 * DD2, (long long)W2SLOT);
  k_gemm3<<<gP2, 256, 0, stream>>>(H1, K2P, W2P, K2P, K2P / 32,
      T, 2 * N2PAD, (const u16*)nullptr, 0, 2 * N2PAD, 2 * N2PAD, NN,
      (const float*)nullptr, 0, 0, MT, 2 * N2PAD / 128);
  k_agg2<<<NN, 256, 0, stream>>>(T, 2 * N2PAD, N2PAD, HACC, K3P, DD2, offsets, ssrc, 2, 0);
  k_transpose<<<g_t2s, tb, 0, stream>>>(root2, DD1, DD2, W2R, K2P, 0, 0);
  k_gemm3<<<gR2, 256, 0, stream>>>(H1, K2P, W2R, K2P, K2P / 32,
      H2, K3P, HACC, K3P, DD2, K3P, NN, b2, 1, 0, MT, N2PAD / 128);

  // ---- lin1 -> emb (f32, straight into d_out) ----
  k_transpose<<<dim3((DD2 + 31) / 32, (DD3 + 31) / 32, 1), tb, 0, stream>>>(
      lin1_w, DD2, DD3, W3T, K3P, 0, 0);
  k_gemm3<<<gL3, 256, 0, stream>>>(H2, K3P, W3T, K3P, K3P / 32,
      emb, DD3, (const u16*)nullptr, 0, DD3, DD3, NN, lin1_b, 1, 1, MT, N3PAD / 128);

  // ---- lin2 + log_softmax ----
  k_lin2<<<(NN + 3) / 4, 256, 0, stream>>>(emb, lin2_w, lin2_b, out);
}

// Round 19
// 922.288 us; speedup vs baseline: 1.0856x; 1.0856x over previous
//
#include <hip/hip_runtime.h>
#include <math.h>

// ---------------- problem constants ----------------
#define N_DRUGS 4000
#define NN      8264            // total nodes
#define IN_DIM  1613
#define NRELS   4
#define DD1     1340
#define DD2     920
#define DD3     740
#define NEDGE   100000
#define NSEG    (NN * NRELS)    // 33056

// padded dims
#define K1P     1632            // IN_DIM -> 51*32
#define K2P     1344            // DD1 -> 42*32
#define K3P     928             // DD2 -> 29*32
#define N1PAD   1408            // DD1 -> 11*128 (weight slot width)
#define N2PAD   1024            // DD2 -> 8*128
#define N3PAD   768             // DD3 -> 6*128
#define MT      65              // ceil(NN/128)

typedef unsigned short u16;
typedef __attribute__((ext_vector_type(8))) short short8;
typedef __attribute__((ext_vector_type(4))) float floatx4;

__device__ __forceinline__ u16 f2bf(float f) {
  union { float f; unsigned u; } v; v.f = f;
  unsigned u = v.u + 0x7fffu + ((v.u >> 16) & 1u);   // RNE
  return (u16)(u >> 16);
}
__device__ __forceinline__ float bf2f(u16 h) {
  union { unsigned u; float f; } v; v.u = ((unsigned)h) << 16;
  return v.f;
}

// async global->LDS DMA, 16 bytes per lane. LDS dest must be wave-uniform
// base + lane*16 (linear); swizzling is done on the GLOBAL source address.
__device__ __forceinline__ void gload16(const u16* g, u16* l) {
  __builtin_amdgcn_global_load_lds(
      (const __attribute__((address_space(1))) unsigned int*)g,
      (__attribute__((address_space(3))) unsigned int*)l, 16, 0, 0);
}

// ---------------- small utility kernels ----------------
__global__ void k_zero_i32(int* p, int n) {
  int i = blockIdx.x * 256 + threadIdx.x;
  if (i < n) p[i] = 0;
}

__global__ void k_zero_u16v(u16* p, long long nvec) {  // zeros 8 u16 per thread
  long long i = (long long)blockIdx.x * 256 + threadIdx.x;
  if (i < nvec) {
    short8 z = {0,0,0,0,0,0,0,0};
    *((short8*)p + i) = z;
  }
}

__global__ void k_copy_i32(const int* a, int* b, int n) {
  int i = blockIdx.x * 256 + threadIdx.x;
  if (i < n) b[i] = a[i];
}

// ---------------- CSR build (counting sort by segment = dst*4 + rel) ------
__global__ void k_hist(const int* __restrict__ ei, const int* __restrict__ et,
                       int* __restrict__ counts) {
  int e = blockIdx.x * 256 + threadIdx.x;
  if (e < NEDGE) {
    int dst = ei[NEDGE + e];
    atomicAdd(&counts[dst * 4 + et[e]], 1);
  }
}

__global__ void k_scan(const int* __restrict__ counts, int* __restrict__ offsets) {
  __shared__ int part[1024];
  int tid = threadIdx.x;
  const int chunk = (NSEG + 1023) / 1024;  // 33
  int lo = tid * chunk, hi = min(lo + chunk, NSEG);
  int s = 0;
  for (int i = lo; i < hi; i++) s += counts[i];
  part[tid] = s;
  __syncthreads();
  for (int off = 1; off < 1024; off <<= 1) {
    int v = (tid >= off) ? part[tid - off] : 0;
    __syncthreads();
    part[tid] += v;
    __syncthreads();
  }
  int base = (tid == 0) ? 0 : part[tid - 1];
  for (int i = lo; i < hi; i++) { offsets[i] = base; base += counts[i]; }
  if (tid == 0) offsets[NSEG] = part[1023];
}

__global__ void k_fill(const int* __restrict__ ei, const int* __restrict__ et,
                       int* __restrict__ cursors, int* __restrict__ ssrc) {
  int e = blockIdx.x * 256 + threadIdx.x;
  if (e < NEDGE) {
    int src = ei[e], dst = ei[NEDGE + e];
    int pos = atomicAdd(&cursors[dst * 4 + et[e]], 1);
    if (pos < NEDGE) ssrc[pos] = src;
  }
}

// ---------------- feature builder: xf = concat(x, gene_emb) in bf16 -------
__global__ void k_build_xf(const float* __restrict__ x, const float* __restrict__ gene,
                           u16* __restrict__ xf) {
  int n = blockIdx.x;
  const float* srow = (n < N_DRUGS) ? (x + (long long)n * IN_DIM)
                                    : (gene + (long long)(n - N_DRUGS) * IN_DIM);
  u16* dst = xf + (long long)n * K1P;
  for (int f = threadIdx.x; f < K1P; f += 256)
    dst[f] = (f < IN_DIM) ? f2bf(srow[f]) : (u16)0;
}

// f32 (K x N, row-major) -> bf16 out[n][k], tiled transpose; batched over z
__global__ void k_transpose(const float* __restrict__ in, int K, int N,
                            u16* __restrict__ out, int ldd,
                            long long strideIn, long long strideOut) {
  __shared__ float t[32][33];
  const float* inp = in + (long long)blockIdx.z * strideIn;
  u16* outp = out + (long long)blockIdx.z * strideOut;
  int k0 = blockIdx.x * 32, n0 = blockIdx.y * 32;
  int tx = threadIdx.x, ty = threadIdx.y;
  for (int i = ty; i < 32; i += 8) {
    int k = k0 + i, n = n0 + tx;
    t[i][tx] = (k < K && n < N) ? inp[(long long)k * N + n] : 0.f;
  }
  __syncthreads();
  for (int i = ty; i < 32; i += 8) {
    int n = n0 + i, k = k0 + tx;
    if (n < N && k < K) outp[(long long)n * ldd + k] = f2bf(t[tx][i]);
  }
}

// per-node mean over gathered T rows for TWO relations, accumulate into bf16
// HACC. short8 (16B/lane); all row strides 16B-aligned. Per-f edge
// accumulation order unchanged -> bit-identical. Tail scalar by thread 0.
__global__ void k_agg2(const u16* __restrict__ T, int ldT, int slotOfs,
                       u16* __restrict__ HACC, int ldH, int F,
                       const int* __restrict__ offsets, const int* __restrict__ ssrc,
                       int rbase, int init) {
  int node = blockIdx.x;
  int s0 = node * 4 + rbase;
  int b0 = offsets[s0],     e0 = offsets[s0 + 1];
  int b1 = offsets[s0 + 1], e1 = offsets[s0 + 2];
  float inv0 = (e0 > b0) ? 1.0f / (float)(e0 - b0) : 0.0f;
  float inv1 = (e1 > b1) ? 1.0f / (float)(e1 - b1) : 0.0f;
  u16* o = HACC + (long long)node * ldH;
  int F8 = F >> 3;                       // 1340/8=167, 920/8=115
  for (int f8 = threadIdx.x; f8 < F8; f8 += 256) {
    int fo = f8 << 3;
    float a0=0.f,a1=0.f,a2=0.f,a3=0.f,a4=0.f,a5=0.f,a6=0.f,a7=0.f;
    for (int e = b0; e < e0; e++) {
      short8 v = *(const short8*)(T + (long long)ssrc[e] * ldT + fo);
      a0 += bf2f((u16)v[0]); a1 += bf2f((u16)v[1]);
      a2 += bf2f((u16)v[2]); a3 += bf2f((u16)v[3]);
      a4 += bf2f((u16)v[4]); a5 += bf2f((u16)v[5]);
      a6 += bf2f((u16)v[6]); a7 += bf2f((u16)v[7]);
    }
    float c0=0.f,c1=0.f,c2=0.f,c3=0.f,c4=0.f,c5=0.f,c6=0.f,c7=0.f;
    for (int e = b1; e < e1; e++) {
      short8 v = *(const short8*)(T + (long long)ssrc[e] * ldT + slotOfs + fo);
      c0 += bf2f((u16)v[0]); c1 += bf2f((u16)v[1]);
      c2 += bf2f((u16)v[2]); c3 += bf2f((u16)v[3]);
      c4 += bf2f((u16)v[4]); c5 += bf2f((u16)v[5]);
      c6 += bf2f((u16)v[6]); c7 += bf2f((u16)v[7]);
    }
    float r0 = a0*inv0 + c0*inv1, r1 = a1*inv0 + c1*inv1;
    float r2 = a2*inv0 + c2*inv1, r3 = a3*inv0 + c3*inv1;
    float r4 = a4*inv0 + c4*inv1, r5 = a5*inv0 + c5*inv1;
    float r6 = a6*inv0 + c6*inv1, r7 = a7*inv0 + c7*inv1;
    if (!init) {
      short8 pv = *(const short8*)(o + fo);
      r0 += bf2f((u16)pv[0]); r1 += bf2f((u16)pv[1]);
      r2 += bf2f((u16)pv[2]); r3 += bf2f((u16)pv[3]);
      r4 += bf2f((u16)pv[4]); r5 += bf2f((u16)pv[5]);
      r6 += bf2f((u16)pv[6]); r7 += bf2f((u16)pv[7]);
    }
    short8 ov;
    ov[0] = (short)f2bf(r0); ov[1] = (short)f2bf(r1);
    ov[2] = (short)f2bf(r2); ov[3] = (short)f2bf(r3);
    ov[4] = (short)f2bf(r4); ov[5] = (short)f2bf(r5);
    ov[6] = (short)f2bf(r6); ov[7] = (short)f2bf(r7);
    *(short8*)(o + fo) = ov;
  }
  if ((F & 7) && threadIdx.x == 0) {       // scalar tail (4 feats for F=1340)
    for (int f = F & ~7; f < F; f++) {
      float a = 0.f, c = 0.f;
      for (int e = b0; e < e0; e++) a += bf2f(T[(long long)ssrc[e] * ldT + f]);
      for (int e = b1; e < e1; e++) c += bf2f(T[(long long)ssrc[e] * ldT + slotOfs + f]);
      float r = a * inv0 + c * inv1;
      if (!init) r += bf2f(o[f]);
      o[f] = f2bf(r);
    }
  }
}

// ---------------- bf16 MFMA GEMMs ----------------
// Round-18 A/B verdict: 4-stage (2 blocks/CU) = 152us LOST to 3-stage
// (~2.4 blocks/CU) = 137us -> occupancy/TLP is binding, not pipeline depth.
// k_gemm3: measured-good 128x128 3-stage (roots + lin1; N not 256-divisible).
// k_gemmW: 128x256 tile, 512 threads (8 waves 2Mx4N), SAME per-wave workload
// and SAME 3-stage counted-vmcnt schedule; LDS 72KB -> 2 blocks/CU =
// 16 waves/CU (~2x TLP vs k_gemm3). Per stage per thread: 1 A + 2 B loads
// (vmcnt(3) steady). Swizzle preserved: B wave-load rows give s(row) =
// (row>>1)&3 with row_b1=row_b0+16 keeping the key; frag rows have
// wn=0 mod 64 -> key = (l16>>1)&3; reads retrieve G[row][qd].
#define TBUF (128 * 32)
#define ATBW (128 * 32)   // A stage, u16
#define BTBW (256 * 32)   // B stage, u16

__global__ __launch_bounds__(256)
void k_gemm3(const u16* __restrict__ A, int lda,
             const u16* __restrict__ B, int ldb, int ksteps,
             void* __restrict__ Cout, int ldc,
             const u16* __restrict__ Cacc, int ldacc,
             int nreal, int nlimit, int mlimit,
             const float* __restrict__ bias, int relu, int f32out,
             int mtiles, int ntiles)
{
  int f = blockIdx.x;
  int xr = f & 7, q = f >> 3;
  int Ma = (mtiles + 7) >> 3;
  int ncol = q / Ma;
  int mi = ((q - ncol * Ma) << 3) + xr;
  if (mi >= mtiles) return;

  __shared__ __align__(16) u16 At[3 * TBUF];   // 24 KB
  __shared__ __align__(16) u16 Bt[3 * TBUF];   // 24 KB
  int tid = threadIdx.x;
  int wave = tid >> 6, lane = tid & 63;
  int wm = (wave >> 1) << 6, wn = (wave & 1) << 6;
  int qd = lane >> 4, l16 = lane & 15;

  const u16* Ag = A + (long long)mi * 128 * lda;
  const u16* Bg = B + (long long)ncol * 128 * ldb;

  int row = tid >> 2, cc = tid & 3;
  int swc = cc ^ ((row >> 1) & 3);
  const u16* gA0 = Ag + (long long)row * lda + swc * 8;
  const u16* gA1 = Ag + (long long)(row + 64) * lda + swc * 8;
  const u16* gB0 = Bg + (long long)row * ldb + swc * 8;
  const u16* gB1 = Bg + (long long)(row + 64) * ldb + swc * 8;
  int d0 = tid * 8;
  int d1 = tid * 8 + 64 * 32;
  int rofs = ((qd ^ ((l16 >> 1) & 3)) << 3);

  unsigned baseA = (unsigned)(unsigned long long)(void*)At;
  unsigned baseB = (unsigned)(unsigned long long)(void*)Bt;
  unsigned offA[4], offB[4];
#pragma unroll
  for (int i = 0; i < 4; i++) {
    offA[i] = (unsigned)(((wm + i * 16 + l16) * 32 + rofs) * 2);
    offB[i] = (unsigned)(((wn + i * 16 + l16) * 32 + rofs) * 2);
  }

  gload16(gA0, At + d0); gload16(gA1, At + d1);
  gload16(gB0, Bt + d0); gload16(gB1, Bt + d1);
  if (ksteps > 1) {
    gload16(gA0 + 32, At + TBUF + d0); gload16(gA1 + 32, At + TBUF + d1);
    gload16(gB0 + 32, Bt + TBUF + d0); gload16(gB1 + 32, Bt + TBUF + d1);
  }

  floatx4 acc[4][4] = {};
  int bs = 0;

  for (int ks = 0; ks < ksteps; ks++) {
    if (ks + 1 < ksteps) asm volatile("s_waitcnt vmcnt(4)" ::: "memory");
    else                 asm volatile("s_waitcnt vmcnt(0)" ::: "memory");
    __builtin_amdgcn_s_barrier();
    __builtin_amdgcn_sched_barrier(0);
    if (ks + 2 < ksteps) {
      int ns = bs + 2; if (ns >= 3) ns -= 3;
      int kb = (ks + 2) * 32;
      u16* An = At + ns * TBUF;
      u16* Bn = Bt + ns * TBUF;
      gload16(gA0 + kb, An + d0); gload16(gA1 + kb, An + d1);
      gload16(gB0 + kb, Bn + d0); gload16(gB1 + kb, Bn + d1);
    }
    unsigned sb = (unsigned)(bs * (TBUF * 2));
    short8 af[4], bfr[4];
#pragma unroll
    for (int i = 0; i < 4; i++)
      asm volatile("ds_read_b128 %0, %1" : "=v"(af[i]) : "v"(baseA + sb + offA[i]));
#pragma unroll
    for (int j = 0; j < 4; j++)
      asm volatile("ds_read_b128 %0, %1" : "=v"(bfr[j]) : "v"(baseB + sb + offB[j]));
    asm volatile("s_waitcnt lgkmcnt(0)" ::: "memory");
    __builtin_amdgcn_sched_barrier(0);
#pragma unroll
    for (int i = 0; i < 4; i++)
#pragma unroll
      for (int j = 0; j < 4; j++)
        acc[i][j] = __builtin_amdgcn_mfma_f32_16x16x32_bf16(af[i], bfr[j], acc[i][j], 0, 0, 0);
    bs++; if (bs >= 3) bs = 0;
  }

#pragma unroll
  for (int i = 0; i < 4; i++) {
#pragma unroll
    for (int j = 0; j < 4; j++) {
      int col = ncol * 128 + wn + j * 16 + l16;
      if (col >= nlimit) continue;
      float bv = (bias && col < nreal) ? bias[col] : 0.f;
#pragma unroll
      for (int rg = 0; rg < 4; rg++) {
        int rowc = mi * 128 + wm + i * 16 + qd * 4 + rg;
        if (rowc >= mlimit) continue;
        float v = 0.f;
        if (col < nreal) {
          v = acc[i][j][rg] + bv;
          if (Cacc) v += bf2f(Cacc[(long long)rowc * ldacc + col]);
          if (relu) v = fmaxf(v, 0.f);
        }
        if (f32out) ((float*)Cout)[(long long)rowc * ldc + col] = v;
        else        ((u16*)Cout)[(long long)rowc * ldc + col] = f2bf(v);
      }
    }
  }
}

// 128(M) x 256(N) tile, 512 threads (8 waves, 2M x 4N). Pair GEMMs only
// (N divisible by 256). No bias/Cacc/relu paths needed but kept for parity.
__global__ __launch_bounds__(512)
void k_gemmW(const u16* __restrict__ A, int lda,
             const u16* __restrict__ B, int ldb, int ksteps,
             void* __restrict__ Cout, int ldc,
             int nlimit, int mlimit,
             int mtiles)
{
  int f = blockIdx.x;
  int xr = f & 7, q = f >> 3;
  int Ma = (mtiles + 7) >> 3;
  int ncol = q / Ma;
  int mi = ((q - ncol * Ma) << 3) + xr;
  if (mi >= mtiles) return;

  __shared__ __align__(16) u16 At[3 * ATBW];   // 24 KB
  __shared__ __align__(16) u16 Bt[3 * BTBW];   // 48 KB  (72 KB total)
  int tid = threadIdx.x;
  int wave = tid >> 6, lane = tid & 63;
  int wm = (wave >> 2) << 6;                   // {0,64}
  int wn = (wave & 3) << 6;                    // {0,64,128,192}
  int qd = lane >> 4, l16 = lane & 15;

  const u16* Ag = A + (long long)mi * 128 * lda;
  const u16* Bg = B + (long long)ncol * 256 * ldb;

  // A: 128 rows x 4 chunks; 512 threads -> 1 chunk each
  int rowA = tid >> 2, ccA = tid & 3;
  int swA = ccA ^ ((rowA >> 1) & 3);
  const u16* gA = Ag + (long long)rowA * lda + swA * 8;
  int dA = tid * 8;                            // linear; row=tid>>2, chunk=tid&3

  // B: 256 rows x 4 chunks; 2 wave-loads per wave (rows w*32+q*16+(lane>>2))
  int rowB0 = (wave << 5) + (lane >> 2);       // q=0
  int rowB1 = rowB0 + 16;                      // q=1 (same swizzle key)
  int ccB = lane & 3;
  int swB = ccB ^ ((rowB0 >> 1) & 3);
  const u16* gB0 = Bg + (long long)rowB0 * ldb + swB * 8;
  const u16* gB1 = Bg + (long long)rowB1 * ldb + swB * 8;
  int dB0 = (wave << 10) + lane * 8;           // (wave*2+0)*512 + lane*8
  int dB1 = dB0 + 512;                         // (wave*2+1)*512 + lane*8

  int rofs = ((qd ^ ((l16 >> 1) & 3)) << 3);
  unsigned baseA = (unsigned)(unsigned long long)(void*)At;
  unsigned baseB = (unsigned)(unsigned long long)(void*)Bt;
  unsigned offA[4], offB[4];
#pragma unroll
  for (int i = 0; i < 4; i++) {
    offA[i] = (unsigned)(((wm + i * 16 + l16) * 32 + rofs) * 2);
    offB[i] = (unsigned)(((wn + i * 16 + l16) * 32 + rofs) * 2);
  }

  // prologue: stages 0,1 (3 loads each per thread)
  gload16(gA, At + dA);
  gload16(gB0, Bt + dB0); gload16(gB1, Bt + dB1);
  if (ksteps > 1) {
    gload16(gA + 32, At + ATBW + dA);
    gload16(gB0 + 32, Bt + BTBW + dB0); gload16(gB1 + 32, Bt + BTBW + dB1);
  }

  floatx4 acc[4][4] = {};
  int bs = 0;

  for (int ks = 0; ks < ksteps; ks++) {
    if (ks + 1 < ksteps) asm volatile("s_waitcnt vmcnt(3)" ::: "memory");
    else                 asm volatile("s_waitcnt vmcnt(0)" ::: "memory");
    __builtin_amdgcn_s_barrier();
    __builtin_amdgcn_sched_barrier(0);
    if (ks + 2 < ksteps) {
      int ns = bs + 2; if (ns >= 3) ns -= 3;
      int kb = (ks + 2) * 32;
      gload16(gA + kb, At + ns * ATBW + dA);
      gload16(gB0 + kb, Bt + ns * BTBW + dB0);
      gload16(gB1 + kb, Bt + ns * BTBW + dB1);
    }
    unsigned sbA = (unsigned)(bs * (ATBW * 2));
    unsigned sbB = (unsigned)(bs * (BTBW * 2));
    short8 af[4], bfr[4];
#pragma unroll
    for (int i = 0; i < 4; i++)
      asm volatile("ds_read_b128 %0, %1" : "=v"(af[i]) : "v"(baseA + sbA + offA[i]));
#pragma unroll
    for (int j = 0; j < 4; j++)
      asm volatile("ds_read_b128 %0, %1" : "=v"(bfr[j]) : "v"(baseB + sbB + offB[j]));
    asm volatile("s_waitcnt lgkmcnt(0)" ::: "memory");
    __builtin_amdgcn_sched_barrier(0);
#pragma unroll
    for (int i = 0; i < 4; i++)
#pragma unroll
      for (int j = 0; j < 4; j++)
        acc[i][j] = __builtin_amdgcn_mfma_f32_16x16x32_bf16(af[i], bfr[j], acc[i][j], 0, 0, 0);
    bs++; if (bs >= 3) bs = 0;
  }

#pragma unroll
  for (int i = 0; i < 4; i++) {
#pragma unroll
    for (int j = 0; j < 4; j++) {
      int col = ncol * 256 + wn + j * 16 + l16;
      if (col >= nlimit) continue;
#pragma unroll
      for (int rg = 0; rg < 4; rg++) {
        int rowc = mi * 128 + wm + i * 16 + qd * 4 + rg;
        if (rowc >= mlimit) continue;
        ((u16*)Cout)[(long long)rowc * ldc + col] = f2bf(acc[i][j][rg]);
      }
    }
  }
}

// ---------------- final tiny layer: logits + log_softmax ----------------
__global__ void k_lin2(const float* __restrict__ emb, const float* __restrict__ w,
                       const float* __restrict__ b, float* __restrict__ out) {
  int node = blockIdx.x * 4 + (threadIdx.x >> 6);
  int lane = threadIdx.x & 63;
  if (node >= NN) return;
  const float* e = emb + (long long)node * DD3;
  float a0 = 0.f, a1 = 0.f;
  for (int f = lane; f < DD3; f += 64) {
    float v = e[f];
    a0 += v * w[2 * f];
    a1 += v * w[2 * f + 1];
  }
  for (int off = 32; off > 0; off >>= 1) {
    a0 += __shfl_down(a0, off);
    a1 += __shfl_down(a1, off);
  }
  if (lane == 0) {
    a0 += b[0]; a1 += b[1];
    float m = fmaxf(a0, a1);
    float ls = m + logf(expf(a0 - m) + expf(a1 - m));
    out[(long long)node * 2]     = a0 - ls;
    out[(long long)node * 2 + 1] = a1 - ls;
  }
}

// ---------------- launch ----------------
extern "C" void kernel_launch(void* const* d_in, const int* in_sizes, int n_in,
                              void* d_out, int out_size, void* d_ws, size_t ws_size,
                              hipStream_t stream)
{
  const float* x      = (const float*)d_in[0];
  const float* gene   = (const float*)d_in[1];
  const float* w_rel1 = (const float*)d_in[2];
  const float* root1  = (const float*)d_in[3];
  const float* b1     = (const float*)d_in[4];
  const float* w_rel2 = (const float*)d_in[5];
  const float* root2  = (const float*)d_in[6];
  const float* b2     = (const float*)d_in[7];
  const float* lin1_w = (const float*)d_in[8];
  const float* lin1_b = (const float*)d_in[9];
  const float* lin2_w = (const float*)d_in[10];
  const float* lin2_b = (const float*)d_in[11];
  const int*   ei     = (const int*)d_in[12];
  const int*   et     = (const int*)d_in[13];
  float* out = (float*)d_out;

  // workspace layout (~142 MB total; known-good budget 155.6 MB)
  char* ws = (char*)d_ws;
  size_t off = 0;
  auto alloc = [&](size_t bytes) -> void* {
    void* p = ws + off;
    off += (bytes + 255) & ~(size_t)255;
    return p;
  };
  const size_t W1SLOT = (size_t)N1PAD * K1P;
  const size_t W2SLOT = (size_t)N2PAD * K2P;
  u16* XF   = (u16*)alloc((size_t)NN * K1P * 2);     // reused as H2 (NN x K3P) later
  u16* T    = (u16*)alloc((size_t)NN * 2 * N1PAD * 2); // 2-slot transform output
  u16* HACC = (u16*)alloc((size_t)NN * K2P * 2);     // bf16 aggregation accumulator
  u16* H1   = (u16*)alloc((size_t)NN * K2P * 2);
  u16* W1P  = (u16*)alloc(2 * W1SLOT * 2);           // pair slot (reused r0r1 -> r2r3)
  u16* W1R  = (u16*)alloc(W1SLOT * 2);               // root slot
  u16* W2P  = (u16*)alloc(2 * W2SLOT * 2);
  u16* W2R  = (u16*)alloc(W2SLOT * 2);
  u16* W3T  = (u16*)alloc((size_t)N3PAD * K3P * 2);
  int* counts  = (int*)alloc((NSEG + 1) * 4);        // reused as cursors
  int* offsets = (int*)alloc((NSEG + 1) * 4);
  int* ssrc    = (int*)alloc((size_t)NEDGE * 4);
  u16* H2 = XF;                                      // alias: XF dead after L1 root GEMM
  float* emb = out + 2 * NN;   // d_out = [log_softmax 8264x2][emb 8264x740]

  if (off > ws_size) return;   // diagnostic: stub-like absmax instead of GPU fault

  // ---- CSR build ----
  k_zero_i32<<<(NSEG + 1 + 255) / 256, 256, 0, stream>>>(counts, NSEG + 1);
  k_hist<<<(NEDGE + 255) / 256, 256, 0, stream>>>(ei, et, counts);
  k_scan<<<1, 1024, 0, stream>>>(counts, offsets);
  k_copy_i32<<<(NSEG + 255) / 256, 256, 0, stream>>>(offsets, counts, NSEG); // counts = cursors
  k_fill<<<(NEDGE + 255) / 256, 256, 0, stream>>>(ei, et, counts, ssrc);

  // ---- weights: zero pads once (transposes never touch pad rows/cols) ----
  long long wtot = 3LL * W1SLOT + 3LL * W2SLOT + (long long)N3PAD * K3P;
  k_zero_u16v<<<(unsigned)((wtot / 8 + 255) / 256), 256, 0, stream>>>(W1P, wtot / 8);
  dim3 tb(32, 8);
  dim3 g_t1((IN_DIM + 31) / 32, (DD1 + 31) / 32, 2);
  dim3 g_t1s((IN_DIM + 31) / 32, (DD1 + 31) / 32, 1);
  dim3 g_t2((DD1 + 31) / 32, (DD2 + 31) / 32, 2);
  dim3 g_t2s((DD1 + 31) / 32, (DD2 + 31) / 32, 1);

  // ---- input features ----
  k_build_xf<<<NN, 256, 0, stream>>>(x, gene, XF);

  // grids
  const int Ma8 = 8 * ((MT + 7) / 8);          // 72
  const int gP1W = Ma8 * (2 * N1PAD / 256);    // 792  (256-wide tiles)
  const int gP2W = Ma8 * (2 * N2PAD / 256);    // 576
  const int gR1 = Ma8 * (N1PAD / 128);         // 792
  const int gR2 = Ma8 * (N2PAD / 128);         // 576
  const int gL3 = Ma8 * (N3PAD / 128);         // 432

  // ---- layer 1 ----
  k_transpose<<<g_t1, tb, 0, stream>>>(w_rel1, IN_DIM, DD1, W1P, K1P,
                                       (long long)IN_DIM * DD1, (long long)W1SLOT);
  k_gemmW<<<gP1W, 512, 0, stream>>>(XF, K1P, W1P, K1P, K1P / 32,
      T, 2 * N1PAD, 2 * N1PAD, NN, MT);
  k_agg2<<<NN, 256, 0, stream>>>(T, 2 * N1PAD, N1PAD, HACC, K2P, DD1, offsets, ssrc, 0, 1);
  k_transpose<<<g_t1, tb, 0, stream>>>(w_rel1 + 2LL * IN_DIM * DD1, IN_DIM, DD1, W1P, K1P,
                                       (long long)IN_DIM * DD1, (long long)W1SLOT);
  k_gemmW<<<gP1W, 512, 0, stream>>>(XF, K1P, W1P, K1P, K1P / 32,
      T, 2 * N1PAD, 2 * N1PAD, NN, MT);
  k_agg2<<<NN, 256, 0, stream>>>(T, 2 * N1PAD, N1PAD, HACC, K2P, DD1, offsets, ssrc, 2, 0);
  k_transpose<<<g_t1s, tb, 0, stream>>>(root1, IN_DIM, DD1, W1R, K1P, 0, 0);
  k_gemm3<<<gR1, 256, 0, stream>>>(XF, K1P, W1R, K1P, K1P / 32,
      H1, K2P, HACC, K2P, DD1, K2P, NN, b1, 1, 0, MT, N1PAD / 128);

  // ---- layer 2 ----
  k_transpose<<<g_t2, tb, 0, stream>>>(w_rel2, DD1, DD2, W2P, K2P,
                                       (long long)DD1 * DD2, (long long)W2SLOT);
  k_gemmW<<<gP2W, 512, 0, stream>>>(H1, K2P, W2P, K2P, K2P / 32,
      T, 2 * N2PAD, 2 * N2PAD, NN, MT);
  k_agg2<<<NN, 256, 0, stream>>>(T, 2 * N2PAD, N2PAD, HACC, K3P, DD2, offsets, ssrc, 0, 1);
  k_transpose<<<g_t2, tb, 0, stream>>>(w_rel2 + 2LL * DD1 * DD2, DD1, DD2, W2P, K2P,
                                       (long long)DD1 * DD2, (long long)W2SLOT);
  k_gemmW<<<gP2W, 512, 0, stream>>>(H1, K2P, W2P, K2P, K2P / 32,
      T, 2 * N2PAD, 2 * N2PAD, NN, MT);
  k_agg2<<<NN, 256, 0, stream>>>(T, 2 * N2PAD, N2PAD, HACC, K3P, DD2, offsets, ssrc, 2, 0);
  k_transpose<<<g_t2s, tb, 0, stream>>>(root2, DD1, DD2, W2R, K2P, 0, 0);
  k_gemm3<<<gR2, 256, 0, stream>>>(H1, K2P, W2R, K2P, K2P / 32,
      H2, K3P, HACC, K3P, DD2, K3P, NN, b2, 1, 0, MT, N2PAD / 128);

  // ---- lin1 -> emb (f32, straight into d_out) ----
  k_transpose<<<dim3((DD2 + 31) / 32, (DD3 + 31) / 32, 1), tb, 0, stream>>>(
      lin1_w, DD2, DD3, W3T, K3P, 0, 0);
  k_gemm3<<<gL3, 256, 0, stream>>>(H2, K3P, W3T, K3P, K3P / 32,
      emb, DD3, (const u16*)nullptr, 0, DD3, DD3, NN, lin1_b, 1, 1, MT, N3PAD / 128);

  // ---- lin2 + log_softmax ----
  k_lin2<<<(NN + 3) / 4, 256, 0, stream>>>(emb, lin2_w, lin2_b, out);
}